// Round 2
// baseline (703.942 us; speedup 1.0000x reference)
//
#include <hip/hip_runtime.h>
#include <hip/hip_bf16.h>

#define CH    32
#define DIM   128
#define DHW   (128*128*128)
#define NVERT 50000
#define NPAD  50048   /* 782 * 64 */

typedef __attribute__((ext_vector_type(4))) float f32x4;
typedef __attribute__((ext_vector_type(8))) short s16x8;

__device__ __forceinline__ float bf2f(unsigned short h) {
    union { unsigned int u; float f; } v; v.u = ((unsigned int)h) << 16; return v.f;
}
__device__ __forceinline__ unsigned short f2b(float f) {
    union { float f; unsigned int u; } v; v.f = f;
    unsigned int u = v.u;
    unsigned int r = u + 0x7fffu + ((u >> 16) & 1u);   // RTNE
    return (unsigned short)(r >> 16);
}

// ---- kernel 1: fp32 [C][D][H][W] -> bf16 [D][H][W][C] (channels-last) ----
// Thread handles 4 consecutive voxels: 32 float4 coalesced loads, 256 B
// contiguous bf16 store. 2048 blocks. HBM: 256 MB in + 128 MB out.
__global__ __launch_bounds__(256) void k_transpose(const float* __restrict__ vf,
                                                   unsigned short* __restrict__ vol) {
    const int gid = blockIdx.x * 256 + threadIdx.x;    // 0 .. DHW/4-1
    const float4* in4 = (const float4*)vf;
    union { uint4 u[16]; unsigned short s[128]; } o;
#pragma unroll
    for (int c = 0; c < 32; ++c) {
        float4 f = in4[(size_t)c * (DHW / 4) + gid];
        o.s[0 * 32 + c] = f2b(f.x);
        o.s[1 * 32 + c] = f2b(f.y);
        o.s[2 * 32 + c] = f2b(f.z);
        o.s[3 * 32 + c] = f2b(f.w);
    }
    uint4* outv = (uint4*)(vol + (size_t)gid * 128);
#pragma unroll
    for (int i = 0; i < 16; ++i) outv[i] = o.u[i];
}

// ---- kernel 2: fold all weights into Et[o][k*32+c'] (bf16) + bias[o] (fp32) ----
// out[n,o] = sum_{k,c} feats[n,k,c] * E[o,c,k] + bias[o], with the diff-vs-center
// and both linear branches folded in (no nonlinearities anywhere).
__global__ __launch_bounds__(1024) void k_weights(
    const float* __restrict__ w_d1, const float* __restrict__ b_d1,
    const float* __restrict__ w_d2, const float* __restrict__ b_d2,
    const float* __restrict__ w_c1, const float* __restrict__ b_c1,
    const float* __restrict__ w_c2, const float* __restrict__ b_c2,
    const float* __restrict__ conv_w, const float* __restrict__ conv_b,
    unsigned short* __restrict__ Et, float* __restrict__ biasOut)
{
    __shared__ float Wd[32 * 32], Wc[32 * 32], bd[32];
    const int t = threadIdx.x;
    const int o = t >> 5, cc = t & 31;
    // Wd = w_d2 @ w_d1, Wc = w_c2 @ w_c1
    float s1 = 0.f, s2 = 0.f;
    for (int j = 0; j < 32; ++j) {
        s1 += w_d2[o * 32 + j] * w_d1[j * 32 + cc];
        s2 += w_c2[o * 32 + j] * w_c1[j * 32 + cc];
    }
    Wd[t] = s1; Wc[t] = s2;
    if (t < 32) {
        float s = b_d2[t];
        for (int j = 0; j < 32; ++j) s += w_d2[t * 32 + j] * b_d1[j];
        bd[t] = s;   // bias of diff-branch after both layers
    }
    __syncthreads();
    // M[o,cc,k] = sum_c conv_w[o,c,k] * Wd[c,cc]; fold diff: E_13 += Wc - sum_k M
    float m[27]; float msum = 0.f;
    for (int k = 0; k < 27; ++k) {
        float s = 0.f;
        for (int c = 0; c < 32; ++c)
            s += conv_w[(o * 32 + c) * 27 + k] * Wd[c * 32 + cc];
        m[k] = s; msum += s;
    }
    const float wc = Wc[o * 32 + cc];
    for (int k = 0; k < 27; ++k) {
        float e = m[k] + (k == 13 ? (wc - msum) : 0.f);
        Et[o * 864 + k * 32 + cc] = f2b(e);
    }
    if (cc == 0) {
        float ba = conv_b[o];
        for (int c = 0; c < 32; ++c) {
            float cs = 0.f;
            for (int k = 0; k < 27; ++k) cs += conv_w[(o * 32 + c) * 27 + k];
            ba += cs * bd[c];
        }
        float bc = b_c2[o];
        for (int j = 0; j < 32; ++j) bc += w_c2[o * 32 + j] * b_c1[j];
        biasOut[o] = ba + bc;
    }
}

// ---- kernel 3: trilinear sampling -> feats[n][k][32] bf16 ----
// 4 lanes per (vertex, shift); each lane handles 8 channels (16 B loads).
__global__ __launch_bounds__(256) void k_sample(const float* __restrict__ verts,
                                                const unsigned short* __restrict__ vol,
                                                unsigned short* __restrict__ feats) {
    const int gid  = blockIdx.x * 256 + threadIdx.x;
    const int task = gid >> 2, sub = gid & 3;
    const int n = task / 27;
    const int k = task - n * 27;
    const int nv = n < NVERT ? n : NVERT - 1;
    const float vx = verts[nv * 3 + 0];
    const float vy = verts[nv * 3 + 1];
    const float vz = verts[nv * 3 + 2];
    // shift[k] = (a[k/9], a[(k/3)%3], a[k%3]) * (8/128), cols (x,y,z); center k=13
    const float sx = (float)(k / 9) - 1.0f;
    const float sy = (float)((k / 3) % 3) - 1.0f;
    const float sz = (float)(k % 3) - 1.0f;
    // align_corners=True border clamp: p = clip((c+1)*0.5*127, 0, 127)
    float fx = (vx + sx * 0.0625f + 1.0f) * 63.5f;
    float fy = (vy + sy * 0.0625f + 1.0f) * 63.5f;
    float fz = (vz + sz * 0.0625f + 1.0f) * 63.5f;
    fx = fminf(fmaxf(fx, 0.f), 127.f);
    fy = fminf(fmaxf(fy, 0.f), 127.f);
    fz = fminf(fmaxf(fz, 0.f), 127.f);
    const int x0 = (int)floorf(fx); const float wx = fx - (float)x0; const int x1 = min(x0 + 1, 127);
    const int y0 = (int)floorf(fy); const float wy = fy - (float)y0; const int y1 = min(y0 + 1, 127);
    const int z0 = (int)floorf(fz); const float wz = fz - (float)z0; const int z1 = min(z0 + 1, 127);
    const float w0x = 1.f - wx, w0y = 1.f - wy, w0z = 1.f - wz;
    const float w000 = w0z * w0y * w0x, w001 = w0z * w0y * wx;
    const float w010 = w0z * wy * w0x,  w011 = w0z * wy * wx;
    const float w100 = wz * w0y * w0x,  w101 = wz * w0y * wx;
    const float w110 = wz * wy * w0x,   w111 = wz * wy * wx;

    const uint4* v4 = (const uint4*)vol;     // voxel -> 4 uint4 (32 bf16)
    const int zy00 = (z0 * 128 + y0) * 128, zy01 = (z0 * 128 + y1) * 128;
    const int zy10 = (z1 * 128 + y0) * 128, zy11 = (z1 * 128 + y1) * 128;
    union U4 { uint4 u; unsigned short s[8]; };
    U4 g000, g001, g010, g011, g100, g101, g110, g111;
    g000.u = v4[(zy00 + x0) * 4 + sub];
    g001.u = v4[(zy00 + x1) * 4 + sub];
    g010.u = v4[(zy01 + x0) * 4 + sub];
    g011.u = v4[(zy01 + x1) * 4 + sub];
    g100.u = v4[(zy10 + x0) * 4 + sub];
    g101.u = v4[(zy10 + x1) * 4 + sub];
    g110.u = v4[(zy11 + x0) * 4 + sub];
    g111.u = v4[(zy11 + x1) * 4 + sub];

    U4 r;
#pragma unroll
    for (int j = 0; j < 8; ++j) {
        float a = bf2f(g000.s[j]) * w000 + bf2f(g001.s[j]) * w001
                + bf2f(g010.s[j]) * w010 + bf2f(g011.s[j]) * w011
                + bf2f(g100.s[j]) * w100 + bf2f(g101.s[j]) * w101
                + bf2f(g110.s[j]) * w110 + bf2f(g111.s[j]) * w111;
        r.s[j] = f2b(a);
    }
    ((uint4*)feats)[gid] = r.u;              // feats element = task*32 + sub*8
}

// ---- kernel 4: out[n][o] = feats[n][:] . Et[o][:] + bias[o], MFMA bf16, fp32 out ----
__global__ __launch_bounds__(256) void k_gemm(const unsigned short* __restrict__ feats,
                                              const unsigned short* __restrict__ Et,
                                              const float* __restrict__ bias,
                                              float* __restrict__ out) {
    const int wave = threadIdx.x >> 6, lane = threadIdx.x & 63;
    const int n0 = blockIdx.x * 64 + wave * 16;
    const int m = lane & 15, q = lane >> 4;
    f32x4 acc0 = {0.f, 0.f, 0.f, 0.f}, acc1 = {0.f, 0.f, 0.f, 0.f};
    // A[m][k]: lane m = vertex row, k = q*8+j contiguous; B^T rows = Et rows (out ch)
    const uint4* A  = (const uint4*)(feats + (size_t)(n0 + m) * 864) + q;
    const uint4* B0 = (const uint4*)(Et + m * 864) + q;
    const uint4* B1 = (const uint4*)(Et + (m + 16) * 864) + q;
#pragma unroll
    for (int kk = 0; kk < 27; ++kk) {
        union { uint4 u; s16x8 v; } a, b0, b1;
        a.u  = A[kk * 4];
        b0.u = B0[kk * 4];
        b1.u = B1[kk * 4];
        acc0 = __builtin_amdgcn_mfma_f32_16x16x32_bf16(a.v, b0.v, acc0, 0, 0, 0);
        acc1 = __builtin_amdgcn_mfma_f32_16x16x32_bf16(a.v, b1.v, acc1, 0, 0, 0);
    }
    const float bi0 = bias[m], bi1 = bias[m + 16];
#pragma unroll
    for (int r = 0; r < 4; ++r) {
        const int n = n0 + q * 4 + r;     // C/D: col=lane&15, row=q*4+r (m89-verified)
        if (n < NVERT) {
            out[n * 32 + m]      = acc0[r] + bi0;
            out[n * 32 + 16 + m] = acc1[r] + bi1;
        }
    }
}

extern "C" void kernel_launch(void* const* d_in, const int* in_sizes, int n_in,
                              void* d_out, int out_size, void* d_ws, size_t ws_size,
                              hipStream_t stream) {
    const float* vf     = (const float*)d_in[0];
    const float* verts  = (const float*)d_in[1];
    const float* w_d1   = (const float*)d_in[2];
    const float* b_d1   = (const float*)d_in[3];
    const float* w_d2   = (const float*)d_in[4];
    const float* b_d2   = (const float*)d_in[5];
    const float* w_c1   = (const float*)d_in[6];
    const float* b_c1   = (const float*)d_in[7];
    const float* w_c2   = (const float*)d_in[8];
    const float* b_c2   = (const float*)d_in[9];
    const float* conv_w = (const float*)d_in[10];
    const float* conv_b = (const float*)d_in[11];

    // ws layout: vol bf16 [DHW][32] (128 MiB) | Et bf16 [32][864] | bias f32 [32] | feats bf16 [NPAD][27][32]
    char* ws = (char*)d_ws;
    unsigned short* vol   = (unsigned short*)ws;                               // 134217728 B
    unsigned short* Et    = (unsigned short*)(ws + 134217728);                 // 55296 B
    float*          bias  = (float*)(ws + 134217728 + 55296);                  // 128 B
    unsigned short* feats = (unsigned short*)(ws + 134217728 + 55296 + 128);   // 86482944 B

    k_transpose<<<DHW / 4 / 256, 256, 0, stream>>>(vf, vol);
    k_weights<<<1, 1024, 0, stream>>>(w_d1, b_d1, w_d2, b_d2, w_c1, b_c1,
                                      w_c2, b_c2, conv_w, conv_b, Et, bias);
    k_sample<<<(NPAD * 27) / 64, 256, 0, stream>>>(verts, vol, feats);
    k_gemm<<<NPAD / 64, 256, 0, stream>>>(feats, Et, bias, (float*)d_out);
}

// Round 4
// 631.190 us; speedup vs baseline: 1.1153x; 1.1153x over previous
//
#include <hip/hip_runtime.h>
#include <hip/hip_bf16.h>

#define CH    32
#define DIM   128
#define DHW   (128*128*128)
#define NVERT 50000
#define NPAD  50048   /* 782 * 64 */

typedef __attribute__((ext_vector_type(4))) float f32x4;
typedef __attribute__((ext_vector_type(8))) short s16x8;

__device__ __forceinline__ float bf2f(unsigned short h) {
    union { unsigned int u; float f; } v; v.u = ((unsigned int)h) << 16; return v.f;
}
__device__ __forceinline__ unsigned short f2b(float f) {
    union { float f; unsigned int u; } v; v.f = f;
    unsigned int u = v.u;
    unsigned int r = u + 0x7fffu + ((u >> 16) & 1u);   // RTNE
    return (unsigned short)(r >> 16);
}

// ---- kernel 1: fp32 [C][D][H][W] -> bf16 [D][H][W][C] ----
// 1 voxel/thread: 32 independent coalesced dword loads (one vmcnt drain),
// 64 B contiguous store per lane. 8192 blocks -> full occupancy.
__global__ __launch_bounds__(256) void k_transpose(const float* __restrict__ vf,
                                                   unsigned short* __restrict__ vol) {
    const int gid = blockIdx.x * 256 + threadIdx.x;    // voxel id
    float v[32];
#pragma unroll
    for (int c = 0; c < 32; ++c) v[c] = vf[(size_t)c * DHW + gid];
    union { uint4 u[4]; unsigned short s[32]; } p;
#pragma unroll
    for (int c = 0; c < 32; ++c) p.s[c] = f2b(v[c]);
    uint4* outv = (uint4*)(vol + (size_t)gid * 32);
#pragma unroll
    for (int i = 0; i < 4; ++i) outv[i] = p.u[i];
}

// ---- kernel 2: fold all weights into Et[o][k*32+c'] (bf16) + bias[o] (fp32) ----
// R2-proven version (1 block). ~10 us, not worth parallelizing risk.
__global__ __launch_bounds__(1024) void k_weights(
    const float* __restrict__ w_d1, const float* __restrict__ b_d1,
    const float* __restrict__ w_d2, const float* __restrict__ b_d2,
    const float* __restrict__ w_c1, const float* __restrict__ b_c1,
    const float* __restrict__ w_c2, const float* __restrict__ b_c2,
    const float* __restrict__ conv_w, const float* __restrict__ conv_b,
    unsigned short* __restrict__ Et, float* __restrict__ biasOut)
{
    __shared__ float Wd[32 * 32], Wc[32 * 32], bd[32];
    const int t = threadIdx.x;
    const int o = t >> 5, cc = t & 31;
    // Wd = w_d2 @ w_d1, Wc = w_c2 @ w_c1
    float s1 = 0.f, s2 = 0.f;
    for (int j = 0; j < 32; ++j) {
        s1 += w_d2[o * 32 + j] * w_d1[j * 32 + cc];
        s2 += w_c2[o * 32 + j] * w_c1[j * 32 + cc];
    }
    Wd[t] = s1; Wc[t] = s2;
    if (t < 32) {
        float s = b_d2[t];
        for (int j = 0; j < 32; ++j) s += w_d2[t * 32 + j] * b_d1[j];
        bd[t] = s;   // bias of diff-branch after both layers
    }
    __syncthreads();
    // M[o,cc,k] = sum_c conv_w[o,c,k] * Wd[c,cc]; fold diff: E_13 += Wc - sum_k M
    float m[27]; float msum = 0.f;
    for (int k = 0; k < 27; ++k) {
        float s = 0.f;
        for (int c = 0; c < 32; ++c)
            s += conv_w[(o * 32 + c) * 27 + k] * Wd[c * 32 + cc];
        m[k] = s; msum += s;
    }
    const float wc = Wc[o * 32 + cc];
    for (int k = 0; k < 27; ++k) {
        float e = m[k] + (k == 13 ? (wc - msum) : 0.f);
        Et[o * 864 + k * 32 + cc] = f2b(e);
    }
    if (cc == 0) {
        float ba = conv_b[o];
        for (int c = 0; c < 32; ++c) {
            float cs = 0.f;
            for (int k = 0; k < 27; ++k) cs += conv_w[(o * 32 + c) * 27 + k];
            ba += cs * bd[c];
        }
        float bc = b_c2[o];
        for (int j = 0; j < 32; ++j) bc += w_c2[o * 32 + j] * b_c1[j];
        biasOut[o] = ba + bc;
    }
}

// ---- kernel 3: trilinear sampling -> feats[n][k][32] bf16 (R2-proven) ----
// 4 lanes per (vertex, shift); each lane handles 8 channels (16 B loads).
__global__ __launch_bounds__(256) void k_sample(const float* __restrict__ verts,
                                                const unsigned short* __restrict__ vol,
                                                unsigned short* __restrict__ feats) {
    const int gid  = blockIdx.x * 256 + threadIdx.x;
    const int task = gid >> 2, sub = gid & 3;
    const int n = task / 27;
    const int k = task - n * 27;
    const int nv = n < NVERT ? n : NVERT - 1;
    const float vx = verts[nv * 3 + 0];
    const float vy = verts[nv * 3 + 1];
    const float vz = verts[nv * 3 + 2];
    // shift[k] = (a[k/9], a[(k/3)%3], a[k%3]) * (8/128), cols (x,y,z); center k=13
    const float sx = (float)(k / 9) - 1.0f;
    const float sy = (float)((k / 3) % 3) - 1.0f;
    const float sz = (float)(k % 3) - 1.0f;
    // align_corners=True border clamp: p = clip((c+1)*0.5*127, 0, 127)
    float fx = (vx + sx * 0.0625f + 1.0f) * 63.5f;
    float fy = (vy + sy * 0.0625f + 1.0f) * 63.5f;
    float fz = (vz + sz * 0.0625f + 1.0f) * 63.5f;
    fx = fminf(fmaxf(fx, 0.f), 127.f);
    fy = fminf(fmaxf(fy, 0.f), 127.f);
    fz = fminf(fmaxf(fz, 0.f), 127.f);
    const int x0 = (int)floorf(fx); const float wx = fx - (float)x0; const int x1 = min(x0 + 1, 127);
    const int y0 = (int)floorf(fy); const float wy = fy - (float)y0; const int y1 = min(y0 + 1, 127);
    const int z0 = (int)floorf(fz); const float wz = fz - (float)z0; const int z1 = min(z0 + 1, 127);
    const float w0x = 1.f - wx, w0y = 1.f - wy, w0z = 1.f - wz;
    const float w000 = w0z * w0y * w0x, w001 = w0z * w0y * wx;
    const float w010 = w0z * wy * w0x,  w011 = w0z * wy * wx;
    const float w100 = wz * w0y * w0x,  w101 = wz * w0y * wx;
    const float w110 = wz * wy * w0x,   w111 = wz * wy * wx;

    const uint4* v4 = (const uint4*)vol;     // voxel -> 4 uint4 (32 bf16)
    const int zy00 = (z0 * 128 + y0) * 128, zy01 = (z0 * 128 + y1) * 128;
    const int zy10 = (z1 * 128 + y0) * 128, zy11 = (z1 * 128 + y1) * 128;
    union U4 { uint4 u; unsigned short s[8]; };
    U4 g000, g001, g010, g011, g100, g101, g110, g111;
    g000.u = v4[(zy00 + x0) * 4 + sub];
    g001.u = v4[(zy00 + x1) * 4 + sub];
    g010.u = v4[(zy01 + x0) * 4 + sub];
    g011.u = v4[(zy01 + x1) * 4 + sub];
    g100.u = v4[(zy10 + x0) * 4 + sub];
    g101.u = v4[(zy10 + x1) * 4 + sub];
    g110.u = v4[(zy11 + x0) * 4 + sub];
    g111.u = v4[(zy11 + x1) * 4 + sub];

    U4 r;
#pragma unroll
    for (int j = 0; j < 8; ++j) {
        float a = bf2f(g000.s[j]) * w000 + bf2f(g001.s[j]) * w001
                + bf2f(g010.s[j]) * w010 + bf2f(g011.s[j]) * w011
                + bf2f(g100.s[j]) * w100 + bf2f(g101.s[j]) * w101
                + bf2f(g110.s[j]) * w110 + bf2f(g111.s[j]) * w111;
        r.s[j] = f2b(a);
    }
    ((uint4*)feats)[gid] = r.u;              // feats element = task*32 + sub*8
}

// ---- kernel 4: out[n][o] = feats[n][:] . Et[o][:] + bias[o], MFMA bf16, fp32 out ----
// (R2-proven)
__global__ __launch_bounds__(256) void k_gemm(const unsigned short* __restrict__ feats,
                                              const unsigned short* __restrict__ Et,
                                              const float* __restrict__ bias,
                                              float* __restrict__ out) {
    const int wave = threadIdx.x >> 6, lane = threadIdx.x & 63;
    const int n0 = blockIdx.x * 64 + wave * 16;
    const int m = lane & 15, q = lane >> 4;
    f32x4 acc0 = {0.f, 0.f, 0.f, 0.f}, acc1 = {0.f, 0.f, 0.f, 0.f};
    // A[m][k]: lane m = vertex row, k = q*8+j contiguous; B^T rows = Et rows (out ch)
    const uint4* A  = (const uint4*)(feats + (size_t)(n0 + m) * 864) + q;
    const uint4* B0 = (const uint4*)(Et + m * 864) + q;
    const uint4* B1 = (const uint4*)(Et + (m + 16) * 864) + q;
#pragma unroll
    for (int kk = 0; kk < 27; ++kk) {
        union { uint4 u; s16x8 v; } a, b0, b1;
        a.u  = A[kk * 4];
        b0.u = B0[kk * 4];
        b1.u = B1[kk * 4];
        acc0 = __builtin_amdgcn_mfma_f32_16x16x32_bf16(a.v, b0.v, acc0, 0, 0, 0);
        acc1 = __builtin_amdgcn_mfma_f32_16x16x32_bf16(a.v, b1.v, acc1, 0, 0, 0);
    }
    const float bi0 = bias[m], bi1 = bias[m + 16];
#pragma unroll
    for (int r = 0; r < 4; ++r) {
        const int n = n0 + q * 4 + r;     // C/D: col=lane&15, row=q*4+r (m89-verified)
        if (n < NVERT) {
            out[n * 32 + m]      = acc0[r] + bi0;
            out[n * 32 + 16 + m] = acc1[r] + bi1;
        }
    }
}

extern "C" void kernel_launch(void* const* d_in, const int* in_sizes, int n_in,
                              void* d_out, int out_size, void* d_ws, size_t ws_size,
                              hipStream_t stream) {
    const float* vf     = (const float*)d_in[0];
    const float* verts  = (const float*)d_in[1];
    const float* w_d1   = (const float*)d_in[2];
    const float* b_d1   = (const float*)d_in[3];
    const float* w_d2   = (const float*)d_in[4];
    const float* b_d2   = (const float*)d_in[5];
    const float* w_c1   = (const float*)d_in[6];
    const float* b_c1   = (const float*)d_in[7];
    const float* w_c2   = (const float*)d_in[8];
    const float* b_c2   = (const float*)d_in[9];
    const float* conv_w = (const float*)d_in[10];
    const float* conv_b = (const float*)d_in[11];

    // ws: vol bf16 [DHW][32] (128 MiB) | Et bf16 [32][864] | bias f32 [32] | feats bf16 [NPAD][27][32]
    char* ws = (char*)d_ws;
    unsigned short* vol   = (unsigned short*)ws;                               // 134217728 B
    unsigned short* Et    = (unsigned short*)(ws + 134217728);                 // 55296 B
    float*          bias  = (float*)(ws + 134217728 + 55296);                  // 128 B
    unsigned short* feats = (unsigned short*)(ws + 134217728 + 55296 + 128);   // 86482944 B

    k_transpose<<<DHW / 256, 256, 0, stream>>>(vf, vol);
    k_weights<<<1, 1024, 0, stream>>>(w_d1, b_d1, w_d2, b_d2, w_c1, b_c1,
                                      w_c2, b_c2, conv_w, conv_b, Et, bias);
    k_sample<<<(NPAD * 27) / 64, 256, 0, stream>>>(verts, vol, feats);
    k_gemm<<<NPAD / 64, 256, 0, stream>>>(feats, Et, bias, (float*)d_out);
}

// Round 5
// 621.006 us; speedup vs baseline: 1.1336x; 1.0164x over previous
//
#include <hip/hip_runtime.h>
#include <hip/hip_bf16.h>

#define CH    32
#define DIM   128
#define DHW   (128*128*128)
#define NVERT 50000
#define NPAD  50048   /* 782 * 64 */

typedef __attribute__((ext_vector_type(4))) float f32x4;
typedef __attribute__((ext_vector_type(8))) short s16x8;

__device__ __forceinline__ float bf2f(unsigned short h) {
    union { unsigned int u; float f; } v; v.u = ((unsigned int)h) << 16; return v.f;
}
__device__ __forceinline__ unsigned short f2b(float f) {
    union { float f; unsigned int u; } v; v.f = f;
    unsigned int u = v.u;
    unsigned int r = u + 0x7fffu + ((u >> 16) & 1u);   // RTNE
    return (unsigned short)(r >> 16);
}

// ---- kernel 1 (v3): fp32 [C][D][H][W] -> bf16 [D][H][W][C] ----
// 4 threads per voxel (cq = t&3 picks channel-quad). Loads: per instr, each
// cq-group of 16 lanes reads 64 B contiguous (4 segments/wave). Stores: lane t
// writes bytes [t*16, t*16+16) of a contiguous 4 KB run -> zero inflation.
__global__ __launch_bounds__(256) void k_transpose(const float* __restrict__ vf,
                                                   unsigned short* __restrict__ vol) {
    const int t  = threadIdx.x;
    const int cq = t & 3;
    const int vo = blockIdx.x * 64 + (t >> 2);       // voxel id
    float v[8];
#pragma unroll
    for (int j = 0; j < 8; ++j) v[j] = vf[(size_t)(cq * 8 + j) * DHW + vo];
    union { uint4 u; unsigned short s[8]; } p;
#pragma unroll
    for (int j = 0; j < 8; ++j) p.s[j] = f2b(v[j]);
    ((uint4*)vol)[vo * 4 + cq] = p.u;
}

// ---- kernel 2a: Wd = w_d2@w_d1 (fp32 -> ws) + folded bias ----
__global__ __launch_bounds__(1024) void k_fold1(
    const float* __restrict__ w_d1, const float* __restrict__ b_d1,
    const float* __restrict__ w_d2, const float* __restrict__ b_d2,
    const float* __restrict__ w_c1, const float* __restrict__ b_c1,
    const float* __restrict__ w_c2, const float* __restrict__ b_c2,
    const float* __restrict__ conv_w, const float* __restrict__ conv_b,
    float* __restrict__ WdG, float* __restrict__ biasOut)
{
    __shared__ float bd[32];
    const int t = threadIdx.x;
    const int o = t >> 5, cc = t & 31;
    float s1 = 0.f;
    for (int j = 0; j < 32; ++j) s1 += w_d2[o * 32 + j] * w_d1[j * 32 + cc];
    WdG[t] = s1;
    if (t < 32) {
        float s = b_d2[t];
        for (int j = 0; j < 32; ++j) s += w_d2[t * 32 + j] * b_d1[j];
        bd[t] = s;   // diff-branch bias after both layers
    }
    __syncthreads();
    if (t < 32) {    // t = o
        float ba = conv_b[t];
        for (int c = 0; c < 32; ++c) {
            float cs = 0.f;
            for (int k = 0; k < 27; ++k) cs += conv_w[(t * 32 + c) * 27 + k];
            ba += cs * bd[c];
        }
        float bc = b_c2[t];
        for (int j = 0; j < 32; ++j) bc += w_c2[t * 32 + j] * b_c1[j];
        biasOut[t] = ba + bc;
    }
}

// ---- kernel 2b: Et[o][k*32+cc] for one shift k per block (27 blocks) ----
// E[o,cc,k] = sum_c conv_w[o,c,k]*Wd[c,cc]; block 13 adds (Wc - sum_k M).
__global__ __launch_bounds__(1024) void k_fold2(
    const float* __restrict__ w_c1, const float* __restrict__ w_c2,
    const float* __restrict__ conv_w, const float* __restrict__ WdG,
    unsigned short* __restrict__ Et)
{
    const int k = blockIdx.x;
    __shared__ float WdL[1024];
    const int t = threadIdx.x;
    WdL[t] = WdG[t];
    __syncthreads();
    const int o = t >> 5, cc = t & 31;
    float s = 0.f;
    for (int c = 0; c < 32; ++c)
        s += conv_w[(o * 32 + c) * 27 + k] * WdL[c * 32 + cc];
    if (k == 13) {
        float wc = 0.f;
        for (int j = 0; j < 32; ++j) wc += w_c2[o * 32 + j] * w_c1[j * 32 + cc];
        float ms = 0.f;
        for (int c = 0; c < 32; ++c) {
            float cs = 0.f;
            for (int kk = 0; kk < 27; ++kk) cs += conv_w[(o * 32 + c) * 27 + kk];
            ms += cs * WdL[c * 32 + cc];
        }
        s += wc - ms;
    }
    Et[o * 864 + k * 32 + cc] = f2b(s);
}

// ---- kernel 3: trilinear sampling -> feats[n][k][32] bf16 (R2-proven, FROZEN) ----
__global__ __launch_bounds__(256) void k_sample(const float* __restrict__ verts,
                                                const unsigned short* __restrict__ vol,
                                                unsigned short* __restrict__ feats) {
    const int gid  = blockIdx.x * 256 + threadIdx.x;
    const int task = gid >> 2, sub = gid & 3;
    const int n = task / 27;
    const int k = task - n * 27;
    const int nv = n < NVERT ? n : NVERT - 1;
    const float vx = verts[nv * 3 + 0];
    const float vy = verts[nv * 3 + 1];
    const float vz = verts[nv * 3 + 2];
    const float sx = (float)(k / 9) - 1.0f;
    const float sy = (float)((k / 3) % 3) - 1.0f;
    const float sz = (float)(k % 3) - 1.0f;
    float fx = (vx + sx * 0.0625f + 1.0f) * 63.5f;
    float fy = (vy + sy * 0.0625f + 1.0f) * 63.5f;
    float fz = (vz + sz * 0.0625f + 1.0f) * 63.5f;
    fx = fminf(fmaxf(fx, 0.f), 127.f);
    fy = fminf(fmaxf(fy, 0.f), 127.f);
    fz = fminf(fmaxf(fz, 0.f), 127.f);
    const int x0 = (int)floorf(fx); const float wx = fx - (float)x0; const int x1 = min(x0 + 1, 127);
    const int y0 = (int)floorf(fy); const float wy = fy - (float)y0; const int y1 = min(y0 + 1, 127);
    const int z0 = (int)floorf(fz); const float wz = fz - (float)z0; const int z1 = min(z0 + 1, 127);
    const float w0x = 1.f - wx, w0y = 1.f - wy, w0z = 1.f - wz;
    const float w000 = w0z * w0y * w0x, w001 = w0z * w0y * wx;
    const float w010 = w0z * wy * w0x,  w011 = w0z * wy * wx;
    const float w100 = wz * w0y * w0x,  w101 = wz * w0y * wx;
    const float w110 = wz * wy * w0x,   w111 = wz * wy * wx;

    const uint4* v4 = (const uint4*)vol;
    const int zy00 = (z0 * 128 + y0) * 128, zy01 = (z0 * 128 + y1) * 128;
    const int zy10 = (z1 * 128 + y0) * 128, zy11 = (z1 * 128 + y1) * 128;
    union U4 { uint4 u; unsigned short s[8]; };
    U4 g000, g001, g010, g011, g100, g101, g110, g111;
    g000.u = v4[(zy00 + x0) * 4 + sub];
    g001.u = v4[(zy00 + x1) * 4 + sub];
    g010.u = v4[(zy01 + x0) * 4 + sub];
    g011.u = v4[(zy01 + x1) * 4 + sub];
    g100.u = v4[(zy10 + x0) * 4 + sub];
    g101.u = v4[(zy10 + x1) * 4 + sub];
    g110.u = v4[(zy11 + x0) * 4 + sub];
    g111.u = v4[(zy11 + x1) * 4 + sub];

    U4 r;
#pragma unroll
    for (int j = 0; j < 8; ++j) {
        float a = bf2f(g000.s[j]) * w000 + bf2f(g001.s[j]) * w001
                + bf2f(g010.s[j]) * w010 + bf2f(g011.s[j]) * w011
                + bf2f(g100.s[j]) * w100 + bf2f(g101.s[j]) * w101
                + bf2f(g110.s[j]) * w110 + bf2f(g111.s[j]) * w111;
        r.s[j] = f2b(a);
    }
    ((uint4*)feats)[gid] = r.u;
}

// ---- kernel 4: MFMA GEMM (R2-proven, FROZEN) ----
__global__ __launch_bounds__(256) void k_gemm(const unsigned short* __restrict__ feats,
                                              const unsigned short* __restrict__ Et,
                                              const float* __restrict__ bias,
                                              float* __restrict__ out) {
    const int wave = threadIdx.x >> 6, lane = threadIdx.x & 63;
    const int n0 = blockIdx.x * 64 + wave * 16;
    const int m = lane & 15, q = lane >> 4;
    f32x4 acc0 = {0.f, 0.f, 0.f, 0.f}, acc1 = {0.f, 0.f, 0.f, 0.f};
    const uint4* A  = (const uint4*)(feats + (size_t)(n0 + m) * 864) + q;
    const uint4* B0 = (const uint4*)(Et + m * 864) + q;
    const uint4* B1 = (const uint4*)(Et + (m + 16) * 864) + q;
#pragma unroll
    for (int kk = 0; kk < 27; ++kk) {
        union { uint4 u; s16x8 v; } a, b0, b1;
        a.u  = A[kk * 4];
        b0.u = B0[kk * 4];
        b1.u = B1[kk * 4];
        acc0 = __builtin_amdgcn_mfma_f32_16x16x32_bf16(a.v, b0.v, acc0, 0, 0, 0);
        acc1 = __builtin_amdgcn_mfma_f32_16x16x32_bf16(a.v, b1.v, acc1, 0, 0, 0);
    }
    const float bi0 = bias[m], bi1 = bias[m + 16];
#pragma unroll
    for (int r = 0; r < 4; ++r) {
        const int n = n0 + q * 4 + r;     // C/D: col=lane&15, row=q*4+r (m89-verified)
        if (n < NVERT) {
            out[n * 32 + m]      = acc0[r] + bi0;
            out[n * 32 + 16 + m] = acc1[r] + bi1;
        }
    }
}

extern "C" void kernel_launch(void* const* d_in, const int* in_sizes, int n_in,
                              void* d_out, int out_size, void* d_ws, size_t ws_size,
                              hipStream_t stream) {
    const float* vf     = (const float*)d_in[0];
    const float* verts  = (const float*)d_in[1];
    const float* w_d1   = (const float*)d_in[2];
    const float* b_d1   = (const float*)d_in[3];
    const float* w_d2   = (const float*)d_in[4];
    const float* b_d2   = (const float*)d_in[5];
    const float* w_c1   = (const float*)d_in[6];
    const float* b_c1   = (const float*)d_in[7];
    const float* w_c2   = (const float*)d_in[8];
    const float* b_c2   = (const float*)d_in[9];
    const float* conv_w = (const float*)d_in[10];
    const float* conv_b = (const float*)d_in[11];

    // ws: vol bf16 [DHW][32] | Et bf16 [32][864] | bias f32[32] | WdG f32[1024] | feats
    char* ws = (char*)d_ws;
    unsigned short* vol   = (unsigned short*)ws;                                      // 134217728 B
    unsigned short* Et    = (unsigned short*)(ws + 134217728);                        // 55296 B
    float*          bias  = (float*)(ws + 134217728 + 55296);                         // 128 B
    float*          WdG   = (float*)(ws + 134217728 + 55296 + 128);                   // 4096 B
    unsigned short* feats = (unsigned short*)(ws + 134217728 + 55296 + 128 + 4096);   // 86482944 B

    k_transpose<<<DHW / 64, 256, 0, stream>>>(vf, vol);
    k_fold1<<<1, 1024, 0, stream>>>(w_d1, b_d1, w_d2, b_d2, w_c1, b_c1,
                                    w_c2, b_c2, conv_w, conv_b, WdG, bias);
    k_fold2<<<27, 1024, 0, stream>>>(w_c1, w_c2, conv_w, WdG, Et);
    k_sample<<<(NPAD * 27) / 64, 256, 0, stream>>>(verts, vol, feats);
    k_gemm<<<NPAD / 64, 256, 0, stream>>>(feats, Et, bias, (float*)d_out);
}